// Round 3
// baseline (210.927 us; speedup 1.0000x reference)
//
#include <hip/hip_runtime.h>
#include <hip/hip_cooperative_groups.h>
#include <stdint.h>

namespace cg = cooperative_groups;

#define H 4
#define DB 64
#define EB 64
#define NQ 4096
#define NK 4096
#define NPOS 13
#define SIM_K 12
#define VAL_K 10
#define OUT_K 12

typedef unsigned long long u64;
typedef unsigned int u32;
typedef unsigned short u16;
typedef unsigned char u8;

// ---- workspace layout (bytes, all 64-aligned) ----
#define OFF_KPLO  0u        // NK u64  (enc bits)            32768
#define OFF_KPHI  32768u    // NK u64  (pos bits)            32768
#define OFF_AQ    65536u    // H*NQ u16                      32768
#define OFF_AK    98304u    // H*NK u16                      32768
#define OFF_PRESW 131072u   // 512 u32 present bitmap         2048
#define OFF_COUNT 133120u   // 1 u32 (+pad)                     64
#define OFF_LIST  133184u   // 16384 u32 task list           65536
#define OFF_SIMB  198720u   // H*64 u64 sim bitmap            2048
#define OFF_VALTB 200768u   // H*DB*16 u64 val-table bitmap  32768
#define OFF_OUTTB 233536u   // DB*64 u64 out-table bitmap    32768
#define OFF_VAL   266304u   // H*4096 u64 val bits/key-word 131072
#define OFF_RES   397376u   // H*4096 u64 agg d-mask        131072

__global__ void __launch_bounds__(256) fused(const int* __restrict__ dec_bits,
                                             const int* __restrict__ enc_bits,
                                             const int* __restrict__ sim_conn,
                                             const float* __restrict__ sim_table,
                                             const float* __restrict__ val_table,
                                             const float* __restrict__ out_table,
                                             const int* __restrict__ val_conn,
                                             const int* __restrict__ out_conn,
                                             float* __restrict__ out,
                                             u8* __restrict__ ws) {
    __shared__ u64 smem[5316];          // 42528 B, reused across phases
    cg::grid_group grid = cg::this_grid();
    const int tid = threadIdx.x;
    const int b = blockIdx.x;           // 0..255
    const int t = b * 256 + tid;        // 0..65535
    const int lane = tid & 63;
    const int wl = tid >> 6;            // wave-in-block 0..3
    const int wv = t >> 6;              // global wave 0..1023

    // ================= Phase A: zero flags, binarize tables, pack, addresses
    if (t < 512) ((u32*)(ws + OFF_PRESW))[t] = 0u;
    if (t == 512) *((u32*)(ws + OFF_COUNT)) = 0u;

    {
        u64* sb = (u64*)(ws + OFF_SIMB);
        for (int wi = wv; wi < H * 64; wi += 1024) {
            u64 m = __ballot(sim_table[wi * 64 + lane] > 0.5f);
            if (lane == 0) sb[wi] = m;
        }
        u64* vb = (u64*)(ws + OFF_VALTB);
        for (int wi = wv; wi < H * DB * 16; wi += 1024) {
            u64 m = __ballot(val_table[wi * 64 + lane] > 0.5f);
            if (lane == 0) vb[wi] = m;
        }
        u64* ob = (u64*)(ws + OFF_OUTTB);
        for (int wi = wv; wi < DB * 64; wi += 1024) {
            u64 m = __ballot(out_table[wi * 64 + lane] > 0.5f);
            if (lane == 0) ob[wi] = m;
        }
    }
    // one wave per row: ballot-pack enc/dec, lanes 0-3 compute per-head addrs
    {
        u16* aq = (u16*)(ws + OFF_AQ);
        u16* ak = (u16*)(ws + OFF_AK);
        for (int r = wv; r < NK; r += 1024) {
            u64 lo = __ballot(enc_bits[r * EB + lane] & 1);
            u64 dv = __ballot(dec_bits[r * DB + lane] & 1);
            u64 hi = (u64)(__brev((u32)r) >> 19);   // 13 pos bits
            if (lane == 0) {
                ((u64*)(ws + OFF_KPLO))[r] = lo;
                ((u64*)(ws + OFF_KPHI))[r] = hi;
            }
            if (lane < 4) {
                int h = lane;
                int a_q = 0, a_k = 0;
#pragma unroll
                for (int j = 0; j < SIM_K; ++j) {
                    int c = sim_conn[h * SIM_K + j];
                    if (c < DB) {
                        a_q |= (int)((dv >> c) & 1ull) << j;
                    } else {
                        int c2 = c - DB;
                        int bit = (c2 < 64) ? (int)((lo >> c2) & 1ull)
                                            : (int)((hi >> (c2 - 64)) & 1ull);
                        a_k |= bit << j;
                    }
                }
                aq[h * NQ + r] = (u16)a_q;
                ak[h * NK + r] = (u16)a_k;
            }
        }
    }
    __threadfence();
    grid.sync();

    // ================= Phase B: present compaction + val bits per key-word
    if (t < H * NQ) {
        int a = ((const u16*)(ws + OFF_AQ))[t];
        int key = ((t >> 12) << 12) | a;
        u32* presw = (u32*)(ws + OFF_PRESW);
        u32 mask = 1u << (key & 31);
        u32 old = atomicOr(&presw[key >> 5], mask);
        if (!(old & mask)) {
            u32 p = atomicAdd((u32*)(ws + OFF_COUNT), 1u);
            ((u32*)(ws + OFF_LIST))[p] = (u32)key;
        }
    }
    {
        int h = b >> 6, w = b & 63;     // block = one (h, key-word)
        u64* klo_s = smem;              // 64
        u64* khi_s = smem + 64;         // 64
        u64* vb_s  = smem + 128;        // 1024
        if (tid < 64) {
            klo_s[tid] = ((const u64*)(ws + OFF_KPLO))[w * 64 + tid];
            khi_s[tid] = ((const u64*)(ws + OFF_KPHI))[w * 64 + tid];
        }
        const u64* vbg = (const u64*)(ws + OFF_VALTB) + h * DB * 16;
        for (int i = tid; i < 64 * 16; i += 256) vb_s[i] = vbg[i];
        __syncthreads();

        int d = tid >> 2, c = tid & 3;
        int conn[VAL_K];
#pragma unroll
        for (int j = 0; j < VAL_K; ++j) conn[j] = val_conn[(h * DB + d) * VAL_K + j];
        u32 chunk = 0;
#pragma unroll 4
        for (int i = 0; i < 16; ++i) {
            int k = (c << 4) + i;
            u64 lo = klo_s[k], hi2 = khi_s[k];
            int addr = 0;
#pragma unroll
            for (int j = 0; j < VAL_K; ++j) {
                int cc = conn[j];
                int bit = (cc < 64) ? (int)((lo >> cc) & 1ull)
                                    : (int)((hi2 >> (cc - 64)) & 1ull);
                addr |= bit << j;
            }
            u64 wvv = vb_s[(d << 4) + (addr >> 6)];
            chunk |= (u32)((wvv >> (addr & 63)) & 1ull) << i;
        }
        ((u16*)(ws + OFF_VAL))[(((h << 12) + (w << 6) + d) << 2) + c] = (u16)chunk;
    }
    __threadfence();
    grid.sync();

    // ================= Phase C: heavy phase over compacted task list
    {
        u16* akp_s  = (u16*)smem;               // 4096 u16 (1024 u64)
        u64* val_s  = smem + 1024;              // 4096 u64
        u64* sim_s  = smem + 5120;              // 64 u64
        u32* sums_s = (u32*)(smem + 5184);      // 256 u32 (128 u64)
        u32* cnt_s  = (u32*)(smem + 5312);      // 4 u32
        const u32 count = *(const u32*)(ws + OFF_COUNT);
        const u32* list = (const u32*)(ws + OFF_LIST);
        for (u32 i = (u32)b; i < count; i += 256) {
            u32 key = list[i];
            int h = (int)(key >> 12), a = (int)(key & 4095);
            const u64* akg = (const u64*)(ws + OFF_AK + (size_t)h * NK * 2);
            const u64* vg  = (const u64*)(ws + OFF_VAL) + ((size_t)h << 12);
            const u64* sg  = (const u64*)(ws + OFF_SIMB) + (h << 6);
            u64* akp_v = (u64*)akp_s;
#pragma unroll
            for (int j = 0; j < 4; ++j) akp_v[tid + 256 * j] = akg[tid + 256 * j];
#pragma unroll
            for (int j = 0; j < 16; ++j) val_s[tid + 256 * j] = vg[tid + 256 * j];
            if (tid < 64) sim_s[tid] = sg[tid];
            __syncthreads();

            u32 sums = 0, cnt = 0;
#pragma unroll
            for (int j = 0; j < 16; ++j) {
                int idx = (((wl << 4) + j) << 6) + lane;
                int addr = a | (int)akp_s[idx];
                int attb = (int)((sim_s[addr >> 6] >> (addr & 63)) & 1ull);
                u64 m = __ballot(attb);
                sums += (u32)__popcll(m & val_s[idx]);
                cnt += (u32)__popcll(m);
            }
            sums_s[wl * 64 + lane] = sums;
            if (lane == 0) cnt_s[wl] = cnt;
            __syncthreads();
            if (tid < 64) {
                u32 tot = sums_s[0 * 64 + lane] + sums_s[1 * 64 + lane] +
                          sums_s[2 * 64 + lane] + sums_s[3 * 64 + lane];
                u32 ct = cnt_s[0] + cnt_s[1] + cnt_s[2] + cnt_s[3];
                int g = (ct > 0u) && (2u * tot >= ct);
                u64 gm = __ballot(g);
                if (lane == 0) ((u64*)(ws + OFF_RES))[key] = gm;
            }
            __syncthreads();
        }
    }
    __threadfence();
    grid.sync();

    // ================= Phase D: per (q,d) output gather
    {
        const u16* aq = (const u16*)(ws + OFF_AQ);
        const u64* res = (const u64*)(ws + OFF_RES);
        const u64* ob = (const u64*)(ws + OFF_OUTTB);
        for (int g = t; g < NQ * DB; g += 65536) {
            int q = g >> 6, d = g & 63;
            u64 c0 = res[0 * 4096 + aq[0 * NQ + q]];
            u64 c1 = res[1 * 4096 + aq[1 * NQ + q]];
            u64 c2 = res[2 * 4096 + aq[2 * NQ + q]];
            u64 c3 = res[3 * 4096 + aq[3 * NQ + q]];
            int addr = 0;
#pragma unroll
            for (int j = 0; j < OUT_K; ++j) {
                int c = out_conn[d * OUT_K + j];
                u64 word = (c & 128) ? ((c & 64) ? c3 : c2) : ((c & 64) ? c1 : c0);
                addr |= (int)((word >> (c & 63)) & 1ull) << j;
            }
            u64 ow = ob[(d << 6) + (addr >> 6)];
            out[g] = ((ow >> (addr & 63)) & 1ull) ? 1.0f : 0.0f;
        }
    }
}

extern "C" void kernel_launch(void* const* d_in, const int* in_sizes, int n_in,
                              void* d_out, int out_size, void* d_ws, size_t ws_size,
                              hipStream_t stream) {
    const int*   dec_bits  = (const int*)d_in[0];
    const int*   enc_bits  = (const int*)d_in[1];
    const int*   sim_conn  = (const int*)d_in[2];
    const float* sim_table = (const float*)d_in[3];
    const int*   val_conn  = (const int*)d_in[4];
    const float* val_table = (const float*)d_in[5];
    const int*   out_conn  = (const int*)d_in[6];
    const float* out_table = (const float*)d_in[7];
    float* out = (float*)d_out;
    u8* ws = (u8*)d_ws;

    void* args[] = {(void*)&dec_bits, (void*)&enc_bits, (void*)&sim_conn,
                    (void*)&sim_table, (void*)&val_table, (void*)&out_table,
                    (void*)&val_conn, (void*)&out_conn, (void*)&out, (void*)&ws};
    hipLaunchCooperativeKernel((void*)fused, dim3(256), dim3(256), args, 0, stream);
}

// Round 4
// 65.426 us; speedup vs baseline: 3.2239x; 3.2239x over previous
//
#include <hip/hip_runtime.h>
#include <stdint.h>

#define H 4
#define DB 64
#define EB 64
#define NQ 4096
#define NK 4096
#define NPOS 13
#define SIM_K 12
#define VAL_K 10
#define OUT_K 12

typedef unsigned long long u64;
typedef unsigned int u32;
typedef unsigned short u16;
typedef unsigned char u8;

// ---- workspace layout (bytes) ----
#define OFF_AQ    0u        // H*4096 u16  addr_q                 32768
#define OFF_AK    32768u    // H*4096 u16  addr_kp                32768
#define OFF_CLAIM 65536u    // H*4096 u32  last-writer claim      65536
#define OFF_SIMB  131072u   // H*64 u64    sim bitmap              2048
#define OFF_OUTTB 133120u   // 4096 u64    out-table bitmap       32768
#define OFF_VAL   165888u   // H*4096 u64  val bits [h][kw][d]   131072
#define OFF_RES   294912u   // H*4096 u64  agg d-mask            131072

// K1: block b=(h,w) packs its 64 rows locally, computes ak/aq, claims,
// val bits (direct float lookups), binarizes sim/out tables. No cross-block deps.
__global__ void __launch_bounds__(256) k1(const int* __restrict__ dec_bits,
                                          const int* __restrict__ enc_bits,
                                          const int* __restrict__ sim_conn,
                                          const float* __restrict__ sim_table,
                                          const float* __restrict__ val_table,
                                          const float* __restrict__ out_table,
                                          const int* __restrict__ val_conn,
                                          u8* __restrict__ ws) {
    const int b = blockIdx.x;            // 0..255
    const int h = b >> 6, w = b & 63;
    const int tid = threadIdx.x, lane = tid & 63, wl = tid >> 6;

    __shared__ u64 klo_s[64], khi_s[64], dq_s[64];

    // pack 64 enc/dec rows (wave wl handles 16 rows)
#pragma unroll 4
    for (int i = wl * 16; i < wl * 16 + 16; ++i) {
        int r = w * 64 + i;
        u64 lo = __ballot(enc_bits[r * EB + lane] & 1);
        u64 dv = __ballot(dec_bits[r * DB + lane] & 1);
        if (lane == 0) {
            klo_s[i] = lo;
            dq_s[i] = dv;
            khi_s[i] = (u64)(__brev((u32)r) >> 19);   // 13 pos bits
        }
    }
    // sim bitmap: this block's 64-entry slice
    if (wl == 0) {
        u64 m = __ballot(sim_table[(h << 12) + w * 64 + lane] > 0.5f);
        if (lane == 0) ((u64*)(ws + OFF_SIMB))[h * 64 + w] = m;
    }
    // out-table bitmap: 16 of 4096 words per block
#pragma unroll
    for (int j = wl * 4; j < wl * 4 + 4; ++j) {
        int W = b * 16 + j;            // word = d*64 + (addr>>6)
        u64 m = __ballot(out_table[(W >> 6) * 4096 + (W & 63) * 64 + lane] > 0.5f);
        if (lane == 0) ((u64*)(ws + OFF_OUTTB))[W] = m;
    }
    __syncthreads();

    if (tid < 64) {                     // addr_kp for this block's 64 keys
        u64 lo = klo_s[tid], hi = khi_s[tid];
        int a_k = 0;
#pragma unroll
        for (int j = 0; j < SIM_K; ++j) {
            int c = sim_conn[h * SIM_K + j];
            if (c >= DB) {
                int c2 = c - DB;
                int bit = (c2 < 64) ? (int)((lo >> c2) & 1ull)
                                    : (int)((hi >> (c2 - 64)) & 1ull);
                a_k |= bit << j;
            }
        }
        ((u16*)(ws + OFF_AK))[(h << 12) + w * 64 + tid] = (u16)a_k;
    } else if (tid < 128) {             // addr_q + claim for 64 queries
        int i = tid - 64;
        u64 dv = dq_s[i];
        int a_q = 0;
#pragma unroll
        for (int j = 0; j < SIM_K; ++j) {
            int c = sim_conn[h * SIM_K + j];
            if (c < DB) a_q |= (int)((dv >> c) & 1ull) << j;
        }
        int q = w * 64 + i;
        ((u16*)(ws + OFF_AQ))[(h << 12) + q] = (u16)a_q;
        ((u32*)(ws + OFF_CLAIM))[(h << 12) | a_q] = (u32)q;  // last-writer-wins
    }

    // val bits: thread (d = tid>>2, chunk c4 = tid&3) -> 16 keys
    {
        int d = tid >> 2, c4 = tid & 3;
        int conn[VAL_K];
#pragma unroll
        for (int j = 0; j < VAL_K; ++j) conn[j] = val_conn[(h * DB + d) * VAL_K + j];
        const float* row = val_table + ((h * DB + d) << VAL_K);
        u32 chunk = 0;
#pragma unroll
        for (int i = 0; i < 16; ++i) {
            int kl = c4 * 16 + i;
            u64 lo = klo_s[kl], hi = khi_s[kl];
            int addr = 0;
#pragma unroll
            for (int j = 0; j < VAL_K; ++j) {
                int cc = conn[j];
                int bit = (cc < 64) ? (int)((lo >> cc) & 1ull)
                                    : (int)((hi >> (cc - 64)) & 1ull);
                addr |= bit << j;
            }
            chunk |= (row[addr] > 0.5f ? 1u : 0u) << i;
        }
        ((u16*)(ws + OFF_VAL))[(((h << 12) + (w << 6) + d) << 2) + c4] = (u16)chunk;
    }
}

// K2: block b=(h,w) checks ownership of its 64 queries' (h,addr_q) tasks and
// runs the heavy popcount phase for owned tasks. Operands prefetched to regs.
__global__ void __launch_bounds__(256) k2(u8* __restrict__ ws) {
    const int b = blockIdx.x;
    const int h = b >> 6, w = b & 63;
    const int tid = threadIdx.x, lane = tid & 63, wl = tid >> 6;

    __shared__ u64 sim_s[64];
    __shared__ u32 owned_s[64];
    __shared__ u32 ntask_s;
    __shared__ u32 sums_s[4][64];
    __shared__ u32 cnt_s[4];

    if (wl == 1) sim_s[lane] = ((const u64*)(ws + OFF_SIMB))[h * 64 + lane];
    if (wl == 0) {                       // wave 0: ownership check
        int q = w * 64 + lane;
        u32 a = ((const u16*)(ws + OFF_AQ))[(h << 12) + q];
        u32 key = (u32)(h << 12) | a;
        int owned = (((const u32*)(ws + OFF_CLAIM))[key] == (u32)q);
        u64 om = __ballot(owned);
        if (lane == 0) ntask_s = (u32)__popcll(om);
        if (owned) owned_s[__popcll(om & ((1ull << lane) - 1ull))] = key;
    }
    __syncthreads();
    const u32 ntask = ntask_s;
    if (ntask == 0) return;

    // prefetch this head's akp/val columns for this thread (shared by all tasks)
    const u16* akg = (const u16*)(ws + OFF_AK) + (h << 12);
    const u64* vg  = (const u64*)(ws + OFF_VAL) + ((size_t)h << 12);
    u32 akv[16];
    u64 vv[16];
#pragma unroll
    for (int jj = 0; jj < 16; ++jj) {
        int kw = wl * 16 + jj;
        akv[jj] = akg[(kw << 6) + lane];
        vv[jj]  = vg[(kw << 6) + lane];
    }

    for (u32 ti = 0; ti < ntask; ++ti) {
        u32 key = owned_s[ti];
        int a = (int)(key & 4095);
        u32 sums = 0, cnt = 0;
#pragma unroll
        for (int jj = 0; jj < 16; ++jj) {
            int addr = a | (int)akv[jj];
            int attb = (int)((sim_s[addr >> 6] >> (addr & 63)) & 1ull);
            u64 m = __ballot(attb);
            sums += (u32)__popcll(m & vv[jj]);
            cnt += (u32)__popcll(m);
        }
        sums_s[wl][lane] = sums;
        if (lane == 0) cnt_s[wl] = cnt;
        __syncthreads();
        if (tid < 64) {
            u32 tot = sums_s[0][lane] + sums_s[1][lane] +
                      sums_s[2][lane] + sums_s[3][lane];
            u32 ct = cnt_s[0] + cnt_s[1] + cnt_s[2] + cnt_s[3];
            int g = (ct > 0u) && (2u * tot >= ct);
            u64 gm = __ballot(g);
            if (lane == 0) ((u64*)(ws + OFF_RES))[key] = gm;
        }
        __syncthreads();
    }
}

// K3: per (q,d) gather 12 bits from the 256-bit agg vector, out-table bit test.
__global__ void __launch_bounds__(256) k3(const int* __restrict__ out_conn,
                                          const u8* __restrict__ ws,
                                          float* __restrict__ out) {
    int g = blockIdx.x * 256 + threadIdx.x;  // 0 .. NQ*DB-1
    int q = g >> 6, d = g & 63;
    const u16* aq = (const u16*)(ws + OFF_AQ);
    const u64* res = (const u64*)(ws + OFF_RES);
    u64 c0 = res[0 * 4096 + aq[0 * 4096 + q]];
    u64 c1 = res[1 * 4096 + aq[1 * 4096 + q]];
    u64 c2 = res[2 * 4096 + aq[2 * 4096 + q]];
    u64 c3 = res[3 * 4096 + aq[3 * 4096 + q]];
    int addr = 0;
#pragma unroll
    for (int j = 0; j < OUT_K; ++j) {
        int c = out_conn[d * OUT_K + j];
        u64 word = (c & 128) ? ((c & 64) ? c3 : c2) : ((c & 64) ? c1 : c0);
        addr |= (int)((word >> (c & 63)) & 1ull) << j;
    }
    u64 ow = ((const u64*)(ws + OFF_OUTTB))[(d << 6) + (addr >> 6)];
    out[g] = ((ow >> (addr & 63)) & 1ull) ? 1.0f : 0.0f;
}

extern "C" void kernel_launch(void* const* d_in, const int* in_sizes, int n_in,
                              void* d_out, int out_size, void* d_ws, size_t ws_size,
                              hipStream_t stream) {
    const int*   dec_bits  = (const int*)d_in[0];
    const int*   enc_bits  = (const int*)d_in[1];
    const int*   sim_conn  = (const int*)d_in[2];
    const float* sim_table = (const float*)d_in[3];
    const int*   val_conn  = (const int*)d_in[4];
    const float* val_table = (const float*)d_in[5];
    const int*   out_conn  = (const int*)d_in[6];
    const float* out_table = (const float*)d_in[7];
    float* out = (float*)d_out;
    u8* ws = (u8*)d_ws;

    hipLaunchKernelGGL(k1, dim3(256), dim3(256), 0, stream,
                       dec_bits, enc_bits, sim_conn, sim_table, val_table,
                       out_table, val_conn, ws);
    hipLaunchKernelGGL(k2, dim3(256), dim3(256), 0, stream, ws);
    hipLaunchKernelGGL(k3, dim3(NQ * DB / 256), dim3(256), 0, stream,
                       out_conn, ws, out);
}

// Round 5
// 27.194 us; speedup vs baseline: 7.7563x; 2.4059x over previous
//
#include <hip/hip_runtime.h>
#include <stdint.h>

#define H 4
#define DB 64
#define EB 64
#define NQ 4096
#define NK 4096
#define NPOS 13
#define SIM_K 12
#define VAL_K 10
#define OUT_K 12

typedef unsigned long long u64;
typedef unsigned int u32;
typedef unsigned short u16;
typedef unsigned char u8;

// ---- workspace layout (bytes) ----
#define OFF_AQ    0u        // H*4096 u16  addr_q                 32768
#define OFF_AK    32768u    // H*4096 u16  addr_kp                32768
#define OFF_CLAIM 65536u    // H*4096 u32  last-writer claim      65536
#define OFF_SIMB  131072u   // H*64 u64    sim bitmap              2048
#define OFF_OUTTB 133120u   // 4096 u64    out-table bitmap       32768
#define OFF_VAL   165888u   // H*4096 u64  val bits [h][kw][d]   131072
#define OFF_RES   294912u   // H*4096 u64  agg d-mask            131072

// K1: block b=(h,w) packs its 64 rows locally, computes ak/aq, claims,
// val bits (direct float lookups), binarizes sim/out tables. No cross-block deps.
__global__ void __launch_bounds__(256) k1(const int* __restrict__ dec_bits,
                                          const int* __restrict__ enc_bits,
                                          const int* __restrict__ sim_conn,
                                          const float* __restrict__ sim_table,
                                          const float* __restrict__ val_table,
                                          const float* __restrict__ out_table,
                                          const int* __restrict__ val_conn,
                                          u8* __restrict__ ws) {
    const int b = blockIdx.x;            // 0..255
    const int h = b >> 6, w = b & 63;
    const int tid = threadIdx.x, lane = tid & 63, wl = tid >> 6;

    __shared__ u64 klo_s[64], khi_s[64], dq_s[64];

    // pack 64 enc/dec rows (wave wl handles 16 rows)
#pragma unroll 4
    for (int i = wl * 16; i < wl * 16 + 16; ++i) {
        int r = w * 64 + i;
        u64 lo = __ballot(enc_bits[r * EB + lane] & 1);
        u64 dv = __ballot(dec_bits[r * DB + lane] & 1);
        if (lane == 0) {
            klo_s[i] = lo;
            dq_s[i] = dv;
            khi_s[i] = (u64)(__brev((u32)r) >> 19);   // 13 pos bits
        }
    }
    // sim bitmap: this block's 64-entry slice
    if (wl == 0) {
        u64 m = __ballot(sim_table[(h << 12) + w * 64 + lane] > 0.5f);
        if (lane == 0) ((u64*)(ws + OFF_SIMB))[h * 64 + w] = m;
    }
    // out-table bitmap: 16 of 4096 words per block
#pragma unroll
    for (int j = wl * 4; j < wl * 4 + 4; ++j) {
        int W = b * 16 + j;            // word = d*64 + (addr>>6)
        u64 m = __ballot(out_table[(W >> 6) * 4096 + (W & 63) * 64 + lane] > 0.5f);
        if (lane == 0) ((u64*)(ws + OFF_OUTTB))[W] = m;
    }
    __syncthreads();

    if (tid < 64) {                     // addr_kp for this block's 64 keys
        u64 lo = klo_s[tid], hi = khi_s[tid];
        int a_k = 0;
#pragma unroll
        for (int j = 0; j < SIM_K; ++j) {
            int c = sim_conn[h * SIM_K + j];
            if (c >= DB) {
                int c2 = c - DB;
                int bit = (c2 < 64) ? (int)((lo >> c2) & 1ull)
                                    : (int)((hi >> (c2 - 64)) & 1ull);
                a_k |= bit << j;
            }
        }
        ((u16*)(ws + OFF_AK))[(h << 12) + w * 64 + tid] = (u16)a_k;
    } else if (tid < 128) {             // addr_q + claim for 64 queries
        int i = tid - 64;
        u64 dv = dq_s[i];
        int a_q = 0;
#pragma unroll
        for (int j = 0; j < SIM_K; ++j) {
            int c = sim_conn[h * SIM_K + j];
            if (c < DB) a_q |= (int)((dv >> c) & 1ull) << j;
        }
        int q = w * 64 + i;
        ((u16*)(ws + OFF_AQ))[(h << 12) + q] = (u16)a_q;
        ((u32*)(ws + OFF_CLAIM))[(h << 12) | a_q] = (u32)q;  // last-writer-wins
    }

    // val bits: thread (d = tid>>2, chunk c4 = tid&3) -> 16 keys
    {
        int d = tid >> 2, c4 = tid & 3;
        int conn[VAL_K];
#pragma unroll
        for (int j = 0; j < VAL_K; ++j) conn[j] = val_conn[(h * DB + d) * VAL_K + j];
        const float* row = val_table + ((h * DB + d) << VAL_K);
        u32 chunk = 0;
#pragma unroll
        for (int i = 0; i < 16; ++i) {
            int kl = c4 * 16 + i;
            u64 lo = klo_s[kl], hi = khi_s[kl];
            int addr = 0;
#pragma unroll
            for (int j = 0; j < VAL_K; ++j) {
                int cc = conn[j];
                int bit = (cc < 64) ? (int)((lo >> cc) & 1ull)
                                    : (int)((hi >> (cc - 64)) & 1ull);
                addr |= bit << j;
            }
            chunk |= (row[addr] > 0.5f ? 1u : 0u) << i;
        }
        ((u16*)(ws + OFF_VAL))[(((h << 12) + (w << 6) + d) << 2) + c4] = (u16)chunk;
    }
}

// K2: task (h,a) is processed by block (h, fib_hash(a)) — balanced, decoupled
// from claimant location. Validity check is initialization-free.
__global__ void __launch_bounds__(256) k2(u8* __restrict__ ws) {
    const int b = blockIdx.x;
    const int h = b >> 6, w = b & 63;
    const int tid = threadIdx.x, lane = tid & 63, wl = tid >> 6;

    __shared__ u64 sim_s[64];
    __shared__ u16 owned_s[4096];
    __shared__ u32 ncnt;
    __shared__ u32 sums_s[4][64];
    __shared__ u32 cnt_s[4];

    if (tid == 0) ncnt = 0u;
    if (wl == 1) sim_s[lane] = ((const u64*)(ws + OFF_SIMB))[h * 64 + lane];
    __syncthreads();

    const u32* claim = (const u32*)(ws + OFF_CLAIM) + (h << 12);
    const u16* aqh   = (const u16*)(ws + OFF_AQ) + (h << 12);
    // scan all 4096 candidate addresses of this head; keep hash==w && valid
    for (int i = wl * 16; i < wl * 16 + 16; ++i) {
        int a = (i << 6) | lane;
        int bucket = (int)(((u32)a * 2654435761u) >> 26);
        int valid = 0;
        if (bucket == w) {
            u32 q = claim[a];
            if (q < (u32)NQ) valid = (aqh[q] == (u16)a);
        }
        u64 om = __ballot(valid);
        u32 base = 0;
        if (lane == 0 && om) base = atomicAdd(&ncnt, (u32)__popcll(om));
        base = __shfl(base, 0);
        if (valid) owned_s[base + (u32)__popcll(om & ((1ull << lane) - 1ull))] = (u16)a;
    }
    __syncthreads();
    const u32 ntask = ncnt;
    if (ntask == 0) return;

    // prefetch this head's akp/val columns for this thread (shared by all tasks)
    const u16* akg = (const u16*)(ws + OFF_AK) + (h << 12);
    const u64* vg  = (const u64*)(ws + OFF_VAL) + ((size_t)h << 12);
    u32 akv[16];
    u64 vv[16];
#pragma unroll
    for (int jj = 0; jj < 16; ++jj) {
        int kw = wl * 16 + jj;
        akv[jj] = akg[(kw << 6) + lane];
        vv[jj]  = vg[(kw << 6) + lane];
    }

    for (u32 ti = 0; ti < ntask; ++ti) {
        int a = (int)owned_s[ti];
        u32 sums = 0, cnt = 0;
#pragma unroll
        for (int jj = 0; jj < 16; ++jj) {
            int addr = a | (int)akv[jj];
            int attb = (int)((sim_s[addr >> 6] >> (addr & 63)) & 1ull);
            u64 m = __ballot(attb);
            sums += (u32)__popcll(m & vv[jj]);
            cnt += (u32)__popcll(m);
        }
        sums_s[wl][lane] = sums;
        if (lane == 0) cnt_s[wl] = cnt;
        __syncthreads();
        if (tid < 64) {
            u32 tot = sums_s[0][lane] + sums_s[1][lane] +
                      sums_s[2][lane] + sums_s[3][lane];
            u32 ct = cnt_s[0] + cnt_s[1] + cnt_s[2] + cnt_s[3];
            int g = (ct > 0u) && (2u * tot >= ct);
            u64 gm = __ballot(g);
            if (lane == 0) ((u64*)(ws + OFF_RES))[(h << 12) | a] = gm;
        }
        __syncthreads();
    }
}

// K3: per (q,d) gather 12 bits from the 256-bit agg vector, out-table bit test.
__global__ void __launch_bounds__(256) k3(const int* __restrict__ out_conn,
                                          const u8* __restrict__ ws,
                                          float* __restrict__ out) {
    int g = blockIdx.x * 256 + threadIdx.x;  // 0 .. NQ*DB-1
    int q = g >> 6, d = g & 63;
    const u16* aq = (const u16*)(ws + OFF_AQ);
    const u64* res = (const u64*)(ws + OFF_RES);
    u64 c0 = res[0 * 4096 + aq[0 * 4096 + q]];
    u64 c1 = res[1 * 4096 + aq[1 * 4096 + q]];
    u64 c2 = res[2 * 4096 + aq[2 * 4096 + q]];
    u64 c3 = res[3 * 4096 + aq[3 * 4096 + q]];
    int addr = 0;
#pragma unroll
    for (int j = 0; j < OUT_K; ++j) {
        int c = out_conn[d * OUT_K + j];
        u64 word = (c & 128) ? ((c & 64) ? c3 : c2) : ((c & 64) ? c1 : c0);
        addr |= (int)((word >> (c & 63)) & 1ull) << j;
    }
    u64 ow = ((const u64*)(ws + OFF_OUTTB))[(d << 6) + (addr >> 6)];
    out[g] = ((ow >> (addr & 63)) & 1ull) ? 1.0f : 0.0f;
}

extern "C" void kernel_launch(void* const* d_in, const int* in_sizes, int n_in,
                              void* d_out, int out_size, void* d_ws, size_t ws_size,
                              hipStream_t stream) {
    const int*   dec_bits  = (const int*)d_in[0];
    const int*   enc_bits  = (const int*)d_in[1];
    const int*   sim_conn  = (const int*)d_in[2];
    const float* sim_table = (const float*)d_in[3];
    const int*   val_conn  = (const int*)d_in[4];
    const float* val_table = (const float*)d_in[5];
    const int*   out_conn  = (const int*)d_in[6];
    const float* out_table = (const float*)d_in[7];
    float* out = (float*)d_out;
    u8* ws = (u8*)d_ws;

    hipLaunchKernelGGL(k1, dim3(256), dim3(256), 0, stream,
                       dec_bits, enc_bits, sim_conn, sim_table, val_table,
                       out_table, val_conn, ws);
    hipLaunchKernelGGL(k2, dim3(256), dim3(256), 0, stream, ws);
    hipLaunchKernelGGL(k3, dim3(NQ * DB / 256), dim3(256), 0, stream,
                       out_conn, ws, out);
}

// Round 6
// 20.357 us; speedup vs baseline: 10.3616x; 1.3359x over previous
//
#include <hip/hip_runtime.h>
#include <stdint.h>

#define H 4
#define DB 64
#define EB 64
#define NQ 4096
#define NK 4096
#define NPOS 13
#define SIM_K 12
#define VAL_K 10
#define OUT_K 12

typedef unsigned long long u64;
typedef unsigned int u32;
typedef unsigned short u16;
typedef unsigned char u8;

// ---- workspace layout (bytes) ----
#define OFF_AQ    0u        // H*4096 u16  addr_q                 32768
#define OFF_AK    32768u    // H*4096 u16  addr_kp                32768
#define OFF_SIMB  65536u    // H*64 u64    sim bitmap              2048
#define OFF_OUTTB 67584u    // 4096 u64    out-table bitmap       32768
#define OFF_VAL   100352u   // H*4096 u64  val bits [h][kw][d]   131072
#define OFF_RES   231424u   // H*4096 u64  agg d-mask            131072

// K1: 1024 blocks = (h, kw, c4); each packs its 16 rows, computes ak/aq for
// them, val-bit chunk for all 64 d, and a slice of the sim/out bitmaps.
__global__ void __launch_bounds__(256) k1(const int* __restrict__ dec_bits,
                                          const int* __restrict__ enc_bits,
                                          const int* __restrict__ sim_conn,
                                          const float* __restrict__ sim_table,
                                          const float* __restrict__ val_table,
                                          const float* __restrict__ out_table,
                                          const int* __restrict__ val_conn,
                                          u8* __restrict__ ws) {
    const int b = blockIdx.x;             // 0..1023
    const int h = b >> 8, t8 = b & 255;
    const int kw = t8 >> 2, c4 = t8 & 3;
    const int r0 = (kw << 6) + (c4 << 4); // first of this block's 16 rows
    const int tid = threadIdx.x, lane = tid & 63, wl = tid >> 6;

    __shared__ u64 klo_s[16], khi_s[16], dq_s[16];

    // pack 16 rows (4 per wave)
#pragma unroll
    for (int i = wl * 4; i < wl * 4 + 4; ++i) {
        int r = r0 + i;
        u64 lo = __ballot(enc_bits[r * EB + lane] & 1);
        u64 dv = __ballot(dec_bits[r * DB + lane] & 1);
        if (lane == 0) {
            klo_s[i] = lo;
            dq_s[i] = dv;
            khi_s[i] = (u64)(__brev((u32)r) >> 19);   // 13 pos bits
        }
    }
    // sim bitmap slice: blocks with c4==0 handle word (h,kw) on wave 1
    if (c4 == 0 && wl == 1) {
        u64 m = __ballot(sim_table[(h << 12) + (kw << 6) + lane] > 0.5f);
        if (lane == 0) ((u64*)(ws + OFF_SIMB))[(h << 6) + kw] = m;
    }
    // out-table bitmap: word W = b*4 + wl  (4096 words total)
    {
        int W = (b << 2) + wl;
        u64 m = __ballot(out_table[((W >> 6) << 12) + ((W & 63) << 6) + lane] > 0.5f);
        if (lane == 0) ((u64*)(ws + OFF_OUTTB))[W] = m;
    }
    __syncthreads();

    if (tid < 16) {                       // addr_kp for the 16 keys
        u64 lo = klo_s[tid], hi = khi_s[tid];
        int a_k = 0;
#pragma unroll
        for (int j = 0; j < SIM_K; ++j) {
            int c = sim_conn[h * SIM_K + j];
            if (c >= DB) {
                int c2 = c - DB;
                int bit = (c2 < 64) ? (int)((lo >> c2) & 1ull)
                                    : (int)((hi >> (c2 - 64)) & 1ull);
                a_k |= bit << j;
            }
        }
        ((u16*)(ws + OFF_AK))[(h << 12) + r0 + tid] = (u16)a_k;
    } else if (tid >= 64 && tid < 80) {   // addr_q for the 16 queries
        int i = tid - 64;
        u64 dv = dq_s[i];
        int a_q = 0;
#pragma unroll
        for (int j = 0; j < SIM_K; ++j) {
            int c = sim_conn[h * SIM_K + j];
            if (c < DB) a_q |= (int)((dv >> c) & 1ull) << j;
        }
        ((u16*)(ws + OFF_AQ))[(h << 12) + r0 + i] = (u16)a_q;
    }

    // val bits: thread (d = tid>>2, sub = tid&3) -> 4 keys, nibble combine
    {
        int d = tid >> 2, sub = tid & 3;
        int conn[VAL_K];
#pragma unroll
        for (int j = 0; j < VAL_K; ++j) conn[j] = val_conn[(h * DB + d) * VAL_K + j];
        const float* row = val_table + ((h * DB + d) << VAL_K);
        u32 nib = 0;
#pragma unroll
        for (int ii = 0; ii < 4; ++ii) {
            int i = (sub << 2) + ii;
            u64 lo = klo_s[i], hi = khi_s[i];
            int addr = 0;
#pragma unroll
            for (int j = 0; j < VAL_K; ++j) {
                int cc = conn[j];
                int bit = (cc < 64) ? (int)((lo >> cc) & 1ull)
                                    : (int)((hi >> (cc - 64)) & 1ull);
                addr |= bit << j;
            }
            nib |= (row[addr] > 0.5f ? 1u : 0u) << ii;
        }
        u32 v = nib << (sub << 2);
        v |= __shfl_xor(v, 1);
        v |= __shfl_xor(v, 2);
        if (sub == 0)
            ((u16*)(ws + OFF_VAL))[(((h << 12) + (kw << 6) + d) << 2) + c4] = (u16)v;
    }
}

// K2: tasks enumerated directly from sim_conn's query-side bit positions.
// Head h has 2^n reachable addr_q values (n = #q-side connections); task v is
// handled by block (h, v&63). No claims, no scan.
__global__ void __launch_bounds__(256) k2(const int* __restrict__ sim_conn,
                                          u8* __restrict__ ws) {
    const int b = blockIdx.x;
    const int h = b >> 6, w = b & 63;
    const int tid = threadIdx.x, lane = tid & 63, wl = tid >> 6;

    __shared__ u64 sim_s[64];
    __shared__ u32 sums_s[4][64];
    __shared__ u32 cnt_s[4];

    if (wl == 1) sim_s[lane] = ((const u64*)(ws + OFF_SIMB))[(h << 6) + lane];

    // enumerate query-side bit positions (uniform scalar work)
    int jp[SIM_K];
    int n = 0;
#pragma unroll
    for (int j = 0; j < SIM_K; ++j) {
        int c = sim_conn[h * SIM_K + j];
        if (c < DB) jp[n++] = j;
    }
    u32 ntot = 1u << n;
    if ((u32)w >= ntot) return;           // uniform per block
    __syncthreads();

    // prefetch this head's akp/val columns (shared by all tasks of this block)
    const u16* akg = (const u16*)(ws + OFF_AK) + (h << 12);
    const u64* vg  = (const u64*)(ws + OFF_VAL) + ((size_t)h << 12);
    u32 akv[16];
    u64 vv[16];
#pragma unroll
    for (int jj = 0; jj < 16; ++jj) {
        int kw = wl * 16 + jj;
        akv[jj] = akg[(kw << 6) + lane];
        vv[jj]  = vg[(kw << 6) + lane];
    }

    for (u32 v = (u32)w; v < ntot; v += 64) {
        int a = 0;
        for (int t = 0; t < n; ++t) a |= (int)((v >> t) & 1u) << jp[t];
        u32 sums = 0, cnt = 0;
#pragma unroll
        for (int jj = 0; jj < 16; ++jj) {
            int addr = a | (int)akv[jj];
            int attb = (int)((sim_s[addr >> 6] >> (addr & 63)) & 1ull);
            u64 m = __ballot(attb);
            sums += (u32)__popcll(m & vv[jj]);
            cnt += (u32)__popcll(m);
        }
        sums_s[wl][lane] = sums;
        if (lane == 0) cnt_s[wl] = cnt;
        __syncthreads();
        if (tid < 64) {
            u32 tot = sums_s[0][lane] + sums_s[1][lane] +
                      sums_s[2][lane] + sums_s[3][lane];
            u32 ct = cnt_s[0] + cnt_s[1] + cnt_s[2] + cnt_s[3];
            int g = (ct > 0u) && (2u * tot >= ct);
            u64 gm = __ballot(g);
            if (lane == 0) ((u64*)(ws + OFF_RES))[(h << 12) | a] = gm;
        }
        __syncthreads();
    }
}

// K3: per (q,d) gather 12 bits from the 256-bit agg vector, out-table bit test.
__global__ void __launch_bounds__(256) k3(const int* __restrict__ out_conn,
                                          const u8* __restrict__ ws,
                                          float* __restrict__ out) {
    int g = blockIdx.x * 256 + threadIdx.x;  // 0 .. NQ*DB-1
    int q = g >> 6, d = g & 63;
    const u16* aq = (const u16*)(ws + OFF_AQ);
    const u64* res = (const u64*)(ws + OFF_RES);
    u64 c0 = res[0 * 4096 + aq[0 * 4096 + q]];
    u64 c1 = res[1 * 4096 + aq[1 * 4096 + q]];
    u64 c2 = res[2 * 4096 + aq[2 * 4096 + q]];
    u64 c3 = res[3 * 4096 + aq[3 * 4096 + q]];
    int addr = 0;
#pragma unroll
    for (int j = 0; j < OUT_K; ++j) {
        int c = out_conn[d * OUT_K + j];
        u64 word = (c & 128) ? ((c & 64) ? c3 : c2) : ((c & 64) ? c1 : c0);
        addr |= (int)((word >> (c & 63)) & 1ull) << j;
    }
    u64 ow = ((const u64*)(ws + OFF_OUTTB))[(d << 6) + (addr >> 6)];
    out[g] = ((ow >> (addr & 63)) & 1ull) ? 1.0f : 0.0f;
}

extern "C" void kernel_launch(void* const* d_in, const int* in_sizes, int n_in,
                              void* d_out, int out_size, void* d_ws, size_t ws_size,
                              hipStream_t stream) {
    const int*   dec_bits  = (const int*)d_in[0];
    const int*   enc_bits  = (const int*)d_in[1];
    const int*   sim_conn  = (const int*)d_in[2];
    const float* sim_table = (const float*)d_in[3];
    const int*   val_conn  = (const int*)d_in[4];
    const float* val_table = (const float*)d_in[5];
    const int*   out_conn  = (const int*)d_in[6];
    const float* out_table = (const float*)d_in[7];
    float* out = (float*)d_out;
    u8* ws = (u8*)d_ws;

    hipLaunchKernelGGL(k1, dim3(1024), dim3(256), 0, stream,
                       dec_bits, enc_bits, sim_conn, sim_table, val_table,
                       out_table, val_conn, ws);
    hipLaunchKernelGGL(k2, dim3(256), dim3(256), 0, stream, sim_conn, ws);
    hipLaunchKernelGGL(k3, dim3(NQ * DB / 256), dim3(256), 0, stream,
                       out_conn, ws, out);
}

// Round 7
// 20.287 us; speedup vs baseline: 10.3969x; 1.0034x over previous
//
#include <hip/hip_runtime.h>
#include <stdint.h>

#define H 4
#define DB 64
#define EB 64
#define NQ 4096
#define NK 4096
#define NPOS 13
#define SIM_K 12
#define VAL_K 10
#define OUT_K 12

typedef unsigned long long u64;
typedef unsigned int u32;
typedef unsigned short u16;
typedef unsigned char u8;

// ---- workspace layout (bytes) ----
#define OFF_AQ    0u        // H*4096 u16  addr_q                 32768
#define OFF_AK    32768u    // H*4096 u16  addr_kp                32768
#define OFF_SIMB  65536u    // H*64 u64    sim bitmap              2048
#define OFF_OUTTB 67584u    // 4096 u64    out-table bitmap       32768
#define OFF_VAL   100352u   // H*4096 u64  val bits [h][kw][d]   131072
#define OFF_RES   231424u   // H*4096 u64  agg d-mask            131072

// K1: 1024 blocks = (h, kw, c4); each packs its 16 rows, computes ak/aq for
// them, val-bit chunk for all 64 d, and a slice of the sim/out bitmaps.
__global__ void __launch_bounds__(256) k1(const int* __restrict__ dec_bits,
                                          const int* __restrict__ enc_bits,
                                          const int* __restrict__ sim_conn,
                                          const float* __restrict__ sim_table,
                                          const float* __restrict__ val_table,
                                          const float* __restrict__ out_table,
                                          const int* __restrict__ val_conn,
                                          u8* __restrict__ ws) {
    const int b = blockIdx.x;             // 0..1023
    const int h = b >> 8, t8 = b & 255;
    const int kw = t8 >> 2, c4 = t8 & 3;
    const int r0 = (kw << 6) + (c4 << 4); // first of this block's 16 rows
    const int tid = threadIdx.x, lane = tid & 63, wl = tid >> 6;

    __shared__ u64 klo_s[16], khi_s[16], dq_s[16];

    // pack 16 rows (4 per wave)
#pragma unroll
    for (int i = wl * 4; i < wl * 4 + 4; ++i) {
        int r = r0 + i;
        u64 lo = __ballot(enc_bits[r * EB + lane] & 1);
        u64 dv = __ballot(dec_bits[r * DB + lane] & 1);
        if (lane == 0) {
            klo_s[i] = lo;
            dq_s[i] = dv;
            khi_s[i] = (u64)(__brev((u32)r) >> 19);   // 13 pos bits
        }
    }
    // sim bitmap slice: blocks with c4==0 handle word (h,kw) on wave 1
    if (c4 == 0 && wl == 1) {
        u64 m = __ballot(sim_table[(h << 12) + (kw << 6) + lane] > 0.5f);
        if (lane == 0) ((u64*)(ws + OFF_SIMB))[(h << 6) + kw] = m;
    }
    // out-table bitmap: word W = b*4 + wl  (4096 words total)
    {
        int W = (b << 2) + wl;
        u64 m = __ballot(out_table[((W >> 6) << 12) + ((W & 63) << 6) + lane] > 0.5f);
        if (lane == 0) ((u64*)(ws + OFF_OUTTB))[W] = m;
    }
    __syncthreads();

    if (tid < 16) {                       // addr_kp for the 16 keys
        u64 lo = klo_s[tid], hi = khi_s[tid];
        int a_k = 0;
#pragma unroll
        for (int j = 0; j < SIM_K; ++j) {
            int c = sim_conn[h * SIM_K + j];
            if (c >= DB) {
                int c2 = c - DB;
                int bit = (c2 < 64) ? (int)((lo >> c2) & 1ull)
                                    : (int)((hi >> (c2 - 64)) & 1ull);
                a_k |= bit << j;
            }
        }
        ((u16*)(ws + OFF_AK))[(h << 12) + r0 + tid] = (u16)a_k;
    } else if (tid >= 64 && tid < 80) {   // addr_q for the 16 queries
        int i = tid - 64;
        u64 dv = dq_s[i];
        int a_q = 0;
#pragma unroll
        for (int j = 0; j < SIM_K; ++j) {
            int c = sim_conn[h * SIM_K + j];
            if (c < DB) a_q |= (int)((dv >> c) & 1ull) << j;
        }
        ((u16*)(ws + OFF_AQ))[(h << 12) + r0 + i] = (u16)a_q;
    }

    // val bits: thread (d = tid>>2, sub = tid&3) -> 4 keys, nibble combine
    {
        int d = tid >> 2, sub = tid & 3;
        int conn[VAL_K];
#pragma unroll
        for (int j = 0; j < VAL_K; ++j) conn[j] = val_conn[(h * DB + d) * VAL_K + j];
        const float* row = val_table + ((h * DB + d) << VAL_K);
        u32 nib = 0;
#pragma unroll
        for (int ii = 0; ii < 4; ++ii) {
            int i = (sub << 2) + ii;
            u64 lo = klo_s[i], hi = khi_s[i];
            int addr = 0;
#pragma unroll
            for (int j = 0; j < VAL_K; ++j) {
                int cc = conn[j];
                int bit = (cc < 64) ? (int)((lo >> cc) & 1ull)
                                    : (int)((hi >> (cc - 64)) & 1ull);
                addr |= bit << j;
            }
            nib |= (row[addr] > 0.5f ? 1u : 0u) << ii;
        }
        u32 v = nib << (sub << 2);
        v |= __shfl_xor(v, 1);
        v |= __shfl_xor(v, 2);
        if (sub == 0)
            ((u16*)(ws + OFF_VAL))[(((h << 12) + (kw << 6) + d) << 2) + c4] = (u16)v;
    }
}

// K2: tasks enumerated directly from sim_conn's query-side bit positions.
// Head h has 2^n reachable addr_q values (n = #q-side connections); task v is
// handled by block (h, v&63). No claims, no scan.
__global__ void __launch_bounds__(256) k2(const int* __restrict__ sim_conn,
                                          u8* __restrict__ ws) {
    const int b = blockIdx.x;
    const int h = b >> 6, w = b & 63;
    const int tid = threadIdx.x, lane = tid & 63, wl = tid >> 6;

    __shared__ u64 sim_s[64];
    __shared__ u32 sums_s[4][64];
    __shared__ u32 cnt_s[4];

    if (wl == 1) sim_s[lane] = ((const u64*)(ws + OFF_SIMB))[(h << 6) + lane];

    // enumerate query-side bit positions (uniform scalar work)
    int jp[SIM_K];
    int n = 0;
#pragma unroll
    for (int j = 0; j < SIM_K; ++j) {
        int c = sim_conn[h * SIM_K + j];
        if (c < DB) jp[n++] = j;
    }
    u32 ntot = 1u << n;
    if ((u32)w >= ntot) return;           // uniform per block
    __syncthreads();

    // prefetch this head's akp/val columns (shared by all tasks of this block)
    const u16* akg = (const u16*)(ws + OFF_AK) + (h << 12);
    const u64* vg  = (const u64*)(ws + OFF_VAL) + ((size_t)h << 12);
    u32 akv[16];
    u64 vv[16];
#pragma unroll
    for (int jj = 0; jj < 16; ++jj) {
        int kw = wl * 16 + jj;
        akv[jj] = akg[(kw << 6) + lane];
        vv[jj]  = vg[(kw << 6) + lane];
    }

    for (u32 v = (u32)w; v < ntot; v += 64) {
        int a = 0;
        for (int t = 0; t < n; ++t) a |= (int)((v >> t) & 1u) << jp[t];
        u32 sums = 0, cnt = 0;
#pragma unroll
        for (int jj = 0; jj < 16; ++jj) {
            int addr = a | (int)akv[jj];
            int attb = (int)((sim_s[addr >> 6] >> (addr & 63)) & 1ull);
            u64 m = __ballot(attb);
            sums += (u32)__popcll(m & vv[jj]);
            cnt += (u32)__popcll(m);
        }
        sums_s[wl][lane] = sums;
        if (lane == 0) cnt_s[wl] = cnt;
        __syncthreads();
        if (tid < 64) {
            u32 tot = sums_s[0][lane] + sums_s[1][lane] +
                      sums_s[2][lane] + sums_s[3][lane];
            u32 ct = cnt_s[0] + cnt_s[1] + cnt_s[2] + cnt_s[3];
            int g = (ct > 0u) && (2u * tot >= ct);
            u64 gm = __ballot(g);
            if (lane == 0) ((u64*)(ws + OFF_RES))[(h << 12) | a] = gm;
        }
        __syncthreads();
    }
}

// K3: one wave per query (q wave-uniform -> scalar broadcast loads for aq/res);
// lane = d. Gather 12 bits from the 256-bit agg vector, out-table bit test.
__global__ void __launch_bounds__(256) k3(const int* __restrict__ out_conn,
                                          const u8* __restrict__ ws,
                                          float* __restrict__ out) {
    const int wl = __builtin_amdgcn_readfirstlane(threadIdx.x >> 6);
    const int lane = threadIdx.x & 63;
    const int q = blockIdx.x * 4 + wl;       // wave-uniform query
    const int d = lane;
    const u16* aq = (const u16*)(ws + OFF_AQ);
    const u64* res = (const u64*)(ws + OFF_RES);
    int a0 = (int)aq[0 * 4096 + q];
    int a1 = (int)aq[1 * 4096 + q];
    int a2 = (int)aq[2 * 4096 + q];
    int a3 = (int)aq[3 * 4096 + q];
    u64 c0 = res[0 * 4096 + a0];
    u64 c1 = res[1 * 4096 + a1];
    u64 c2 = res[2 * 4096 + a2];
    u64 c3 = res[3 * 4096 + a3];
    int addr = 0;
#pragma unroll
    for (int j = 0; j < OUT_K; ++j) {
        int c = out_conn[d * OUT_K + j];
        u64 word = (c & 128) ? ((c & 64) ? c3 : c2) : ((c & 64) ? c1 : c0);
        addr |= (int)((word >> (c & 63)) & 1ull) << j;
    }
    u64 ow = ((const u64*)(ws + OFF_OUTTB))[(d << 6) + (addr >> 6)];
    out[(q << 6) + d] = ((ow >> (addr & 63)) & 1ull) ? 1.0f : 0.0f;
}

extern "C" void kernel_launch(void* const* d_in, const int* in_sizes, int n_in,
                              void* d_out, int out_size, void* d_ws, size_t ws_size,
                              hipStream_t stream) {
    const int*   dec_bits  = (const int*)d_in[0];
    const int*   enc_bits  = (const int*)d_in[1];
    const int*   sim_conn  = (const int*)d_in[2];
    const float* sim_table = (const float*)d_in[3];
    const int*   val_conn  = (const int*)d_in[4];
    const float* val_table = (const float*)d_in[5];
    const int*   out_conn  = (const int*)d_in[6];
    const float* out_table = (const float*)d_in[7];
    float* out = (float*)d_out;
    u8* ws = (u8*)d_ws;

    hipLaunchKernelGGL(k1, dim3(1024), dim3(256), 0, stream,
                       dec_bits, enc_bits, sim_conn, sim_table, val_table,
                       out_table, val_conn, ws);
    hipLaunchKernelGGL(k2, dim3(256), dim3(256), 0, stream, sim_conn, ws);
    hipLaunchKernelGGL(k3, dim3(NQ * DB / 256), dim3(256), 0, stream,
                       out_conn, ws, out);
}